// Round 1
// baseline (797.523 us; speedup 1.0000x reference)
//
#include <hip/hip_runtime.h>

#define BB 8
#define SS 2048
#define DD 1024
#define LDK 40   // padded LDS K-stride (bf16 elems): 80 B rows -> 2-way conflicts (free)

typedef unsigned short u16;
typedef __bf16 bf16x8 __attribute__((ext_vector_type(8)));
typedef float f32x4 __attribute__((ext_vector_type(4)));

__device__ __forceinline__ u16 f2bf(float f) {
  unsigned int u = __builtin_bit_cast(unsigned int, f);
  u += 0x7fffu + ((u >> 16) & 1u);   // RNE
  return (u16)(u >> 16);
}

// ---------------- transpose kernels ----------------
// Wt[n][k] = bf16(W[k][n]); W is [DD][DD] fp32
__global__ void wt_transpose(const float* __restrict__ W, u16* __restrict__ Wt) {
  __shared__ u16 t[32][33];
  int n0 = blockIdx.x * 32, k0 = blockIdx.y * 32;
  int tx = threadIdx.x & 31, ty = threadIdx.x >> 5;
#pragma unroll
  for (int i = 0; i < 32; i += 8)
    t[ty + i][tx] = f2bf(W[(size_t)(k0 + ty + i) * DD + n0 + tx]);
  __syncthreads();
#pragma unroll
  for (int i = 0; i < 32; i += 8)
    Wt[(size_t)(n0 + ty + i) * DD + k0 + tx] = t[tx][ty + i];
}

// Vt[b][d][s] = Vb[b][s][d]  (bf16 -> bf16)
__global__ void vt_transpose(const u16* __restrict__ Vsd, u16* __restrict__ Vds) {
  __shared__ u16 t[32][33];
  int b = blockIdx.z;
  int d0 = blockIdx.x * 32, s0 = blockIdx.y * 32;
  const u16* src = Vsd + (size_t)b * SS * DD;
  u16* dst = Vds + (size_t)b * SS * DD;
  int tx = threadIdx.x & 31, ty = threadIdx.x >> 5;
#pragma unroll
  for (int i = 0; i < 32; i += 8)
    t[ty + i][tx] = src[(size_t)(s0 + ty + i) * DD + d0 + tx];
  __syncthreads();
#pragma unroll
  for (int i = 0; i < 32; i += 8)
    dst[(size_t)(d0 + ty + i) * SS + s0 + tx] = t[tx][ty + i];
}

// ---------------- shared MFMA tile body ----------------
// As[m][k], Bs[n][k] (both LDK-strided bf16). Wave computes 64x64 via 4x4 of 16x16x32.
// A-frag: A[m=lane&15][k=quad*8+j]; B-frag: B[k=quad*8+j][n=lane&15]; D: col=lane&15,row=quad*4+r.
__device__ __forceinline__ void mfma_tile(const u16* As, const u16* Bs, int wm, int wn,
                                          int quad, int l16, f32x4 (&acc)[4][4]) {
  bf16x8 a[4], b[4];
#pragma unroll
  for (int i = 0; i < 4; i++)
    a[i] = *reinterpret_cast<const bf16x8*>(&As[(wm + i * 16 + l16) * LDK + quad * 8]);
#pragma unroll
  for (int j = 0; j < 4; j++)
    b[j] = *reinterpret_cast<const bf16x8*>(&Bs[(wn + j * 16 + l16) * LDK + quad * 8]);
#pragma unroll
  for (int i = 0; i < 4; i++)
#pragma unroll
    for (int j = 0; j < 4; j++)
      acc[i][j] = __builtin_amdgcn_mfma_f32_16x16x32_bf16(a[i], b[j], acc[i][j], 0, 0, 0);
}

// ---------------- projection GEMM: Out[m][n] = bf16(X[m][:] @ W[:][n] + bias[n]) ----------------
// X fp32 [16384][1024] (converted to bf16 at staging), Wt bf16 [n][k], Out bf16.
__global__ void proj_gemm(const float* __restrict__ X, const u16* __restrict__ Wt,
                          const float* __restrict__ bias, u16* __restrict__ Out) {
  __shared__ __align__(16) u16 As[128 * LDK];
  __shared__ __align__(16) u16 Bs[128 * LDK];
  int bn = blockIdx.x, bm = blockIdx.y;
  int m0 = bm * 128, n0 = bn * 128;
  int tid = threadIdx.x;
  int lane = tid & 63, wave = tid >> 6;
  int wm = (wave >> 1) * 64, wn = (wave & 1) * 64;
  int quad = lane >> 4, l16 = lane & 15;

  f32x4 acc[4][4];
  f32x4 z = {0.f, 0.f, 0.f, 0.f};
#pragma unroll
  for (int i = 0; i < 4; i++)
#pragma unroll
    for (int j = 0; j < 4; j++) acc[i][j] = z;

  int ar = tid >> 3, ac4 = (tid & 7) * 4;  // A: 8 float4 per 32-float row
  int br = tid >> 2, bc8 = (tid & 3) * 8;  // B: 4 int4 per 32-bf16 row

  for (int k0 = 0; k0 < DD; k0 += 32) {
    __syncthreads();
#pragma unroll
    for (int rr = ar; rr < 128; rr += 32) {
      float4 v = *reinterpret_cast<const float4*>(&X[(size_t)(m0 + rr) * DD + k0 + ac4]);
      uint2 p;
      p.x = (unsigned)f2bf(v.x) | ((unsigned)f2bf(v.y) << 16);
      p.y = (unsigned)f2bf(v.z) | ((unsigned)f2bf(v.w) << 16);
      *reinterpret_cast<uint2*>(&As[rr * LDK + ac4]) = p;
    }
#pragma unroll
    for (int rr = br; rr < 128; rr += 64) {
      *reinterpret_cast<int4*>(&Bs[rr * LDK + bc8]) =
          *reinterpret_cast<const int4*>(&Wt[(size_t)(n0 + rr) * DD + k0 + bc8]);
    }
    __syncthreads();
    mfma_tile(As, Bs, wm, wn, quad, l16, acc);
  }
#pragma unroll
  for (int i = 0; i < 4; i++) {
#pragma unroll
    for (int r = 0; r < 4; r++) {
      int row = m0 + wm + i * 16 + quad * 4 + r;
#pragma unroll
      for (int j = 0; j < 4; j++) {
        int col = n0 + wn + j * 16 + l16;
        Out[(size_t)row * DD + col] = f2bf(acc[i][j][r] + bias[col]);
      }
    }
  }
}

// ---------------- causal scores GEMM: Sc[b][i][j] = (Q[i]·K[j])/32 for j<=i ----------------
__global__ void scores_gemm(const u16* __restrict__ Q, const u16* __restrict__ Kp,
                            float* __restrict__ Sc) {
  int bn = blockIdx.x, bm = blockIdx.y, b = blockIdx.z;
  if (bn > bm) return;  // fully masked tile
  __shared__ __align__(16) u16 As[128 * LDK];
  __shared__ __align__(16) u16 Bs[128 * LDK];
  const u16* Qb = Q + (size_t)b * SS * DD;
  const u16* Kb = Kp + (size_t)b * SS * DD;
  float* Sb = Sc + (size_t)b * SS * SS;
  int m0 = bm * 128, n0 = bn * 128;
  int tid = threadIdx.x;
  int lane = tid & 63, wave = tid >> 6;
  int wm = (wave >> 1) * 64, wn = (wave & 1) * 64;
  int quad = lane >> 4, l16 = lane & 15;

  f32x4 acc[4][4];
  f32x4 z = {0.f, 0.f, 0.f, 0.f};
#pragma unroll
  for (int i = 0; i < 4; i++)
#pragma unroll
    for (int j = 0; j < 4; j++) acc[i][j] = z;

  int sr = tid >> 2, sc8 = (tid & 3) * 8;
  for (int k0 = 0; k0 < DD; k0 += 32) {
    __syncthreads();
#pragma unroll
    for (int rr = sr; rr < 128; rr += 64) {
      *reinterpret_cast<int4*>(&As[rr * LDK + sc8]) =
          *reinterpret_cast<const int4*>(&Qb[(size_t)(m0 + rr) * DD + k0 + sc8]);
      *reinterpret_cast<int4*>(&Bs[rr * LDK + sc8]) =
          *reinterpret_cast<const int4*>(&Kb[(size_t)(n0 + rr) * DD + k0 + sc8]);
    }
    __syncthreads();
    mfma_tile(As, Bs, wm, wn, quad, l16, acc);
  }
#pragma unroll
  for (int i = 0; i < 4; i++) {
#pragma unroll
    for (int r = 0; r < 4; r++) {
      int gi = m0 + wm + i * 16 + quad * 4 + r;
#pragma unroll
      for (int j = 0; j < 4; j++) {
        int gj = n0 + wn + j * 16 + l16;
        if (gj <= gi) Sb[(size_t)gi * SS + gj] = acc[i][j][r] * 0.03125f;
      }
    }
  }
}

// ---------------- row softmax, causal, fp32 -> bf16 P (zeros above diagonal) ----------------
__global__ void softmax_causal(const float* __restrict__ Sc, u16* __restrict__ P) {
  int i = blockIdx.x, b = blockIdx.y;
  const float* srow = Sc + ((size_t)b * SS + i) * SS;
  u16* prow = P + ((size_t)b * SS + i) * SS;
  int n = i + 1;
  int tid = threadIdx.x;
  int lane = tid & 63, wave = tid >> 6;
  __shared__ float sm[4];
  __shared__ float ssum[4];

  float v[8];
  float mx = -3.0e38f;
#pragma unroll
  for (int u = 0; u < 8; u++) {
    int j = tid + u * 256;
    v[u] = (j < n) ? srow[j] : -3.0e38f;
    mx = fmaxf(mx, v[u]);
  }
#pragma unroll
  for (int off = 32; off > 0; off >>= 1) mx = fmaxf(mx, __shfl_down(mx, off, 64));
  if (lane == 0) sm[wave] = mx;
  __syncthreads();
  mx = fmaxf(fmaxf(sm[0], sm[1]), fmaxf(sm[2], sm[3]));

  float e[8];
  float sum = 0.f;
#pragma unroll
  for (int u = 0; u < 8; u++) {
    e[u] = __expf(v[u] - mx);  // v=-3e38 -> exp -> 0 naturally
    sum += e[u];
  }
#pragma unroll
  for (int off = 32; off > 0; off >>= 1) sum += __shfl_down(sum, off, 64);
  if (lane == 0) ssum[wave] = sum;
  __syncthreads();
  sum = ssum[0] + ssum[1] + ssum[2] + ssum[3];
  float inv = 1.0f / sum;
#pragma unroll
  for (int u = 0; u < 8; u++) {
    int j = tid + u * 256;
    prow[j] = f2bf(e[u] * inv);
  }
}

// ---------------- PV GEMM: O[b][i][d] = P[b][i][:] @ V[b][:][d], causal K-loop skip ----------------
__global__ void pv_gemm(const u16* __restrict__ P, const u16* __restrict__ Vt,
                        float* __restrict__ O) {
  int bn = blockIdx.x, bm = blockIdx.y, b = blockIdx.z;
  __shared__ __align__(16) u16 As[128 * LDK];
  __shared__ __align__(16) u16 Bs[128 * LDK];
  const u16* Pb = P + (size_t)b * SS * SS;
  const u16* Vb = Vt + (size_t)b * SS * DD;  // [d][s]
  float* Ob = O + (size_t)b * SS * DD;
  int m0 = bm * 128, n0 = bn * 128;
  int tid = threadIdx.x;
  int lane = tid & 63, wave = tid >> 6;
  int wm = (wave >> 1) * 64, wn = (wave & 1) * 64;
  int quad = lane >> 4, l16 = lane & 15;

  f32x4 acc[4][4];
  f32x4 z = {0.f, 0.f, 0.f, 0.f};
#pragma unroll
  for (int i = 0; i < 4; i++)
#pragma unroll
    for (int j = 0; j < 4; j++) acc[i][j] = z;

  int sr = tid >> 2, sc8 = (tid & 3) * 8;
  int kmax = (bm + 1) * 128;  // P[m][k]==0 for k>m; rows in tile have m <= m0+127
  for (int k0 = 0; k0 < kmax; k0 += 32) {
    __syncthreads();
#pragma unroll
    for (int rr = sr; rr < 128; rr += 64) {
      *reinterpret_cast<int4*>(&As[rr * LDK + sc8]) =
          *reinterpret_cast<const int4*>(&Pb[(size_t)(m0 + rr) * SS + k0 + sc8]);
      *reinterpret_cast<int4*>(&Bs[rr * LDK + sc8]) =
          *reinterpret_cast<const int4*>(&Vb[(size_t)(n0 + rr) * SS + k0 + sc8]);
    }
    __syncthreads();
    mfma_tile(As, Bs, wm, wn, quad, l16, acc);
  }
#pragma unroll
  for (int i = 0; i < 4; i++) {
#pragma unroll
    for (int r = 0; r < 4; r++) {
      int row = m0 + wm + i * 16 + quad * 4 + r;
#pragma unroll
      for (int j = 0; j < 4; j++) {
        int col = n0 + wn + j * 16 + l16;
        Ob[(size_t)row * DD + col] = acc[i][j][r];
      }
    }
  }
}

extern "C" void kernel_launch(void* const* d_in, const int* in_sizes, int n_in,
                              void* d_out, int out_size, void* d_ws, size_t ws_size,
                              hipStream_t stream) {
  const float* query = (const float*)d_in[0];
  const float* key_ = (const float*)d_in[1];
  const float* value = (const float*)d_in[2];
  // d_in[3] = causal mask (tril) -- implemented structurally, not read
  const float* Wq = (const float*)d_in[4];
  const float* bq = (const float*)d_in[5];
  const float* Wk = (const float*)d_in[6];
  const float* bk = (const float*)d_in[7];
  const float* Wv = (const float*)d_in[8];
  const float* bv = (const float*)d_in[9];
  float* out = (float*)d_out;
  char* ws = (char*)d_ws;

  // Workspace layout (224 MiB) with lifetime aliasing:
  //  [0,32M)    Qb bf16          -> later P (first half)
  //  [32M,64M)  Kb bf16          -> later P (second half)
  //  [64M,96M)  Vb bf16          -> later Sc (first part)
  //  [64M,192M) Sc fp32 (after Vb dead)
  //  [192M,..)  Wqt/Wkt/Wvt bf16 -> later Vt bf16 (after proj done)
  u16* Qb = (u16*)(ws + 0);
  u16* Kb = (u16*)(ws + 33554432ull);
  u16* Vb = (u16*)(ws + 67108864ull);
  float* Sc = (float*)(ws + 67108864ull);   // overwrites Vb only after vt_transpose ran
  u16* Wqt = (u16*)(ws + 201326592ull);
  u16* Wkt = (u16*)(ws + 203423744ull);
  u16* Wvt = (u16*)(ws + 205520896ull);
  u16* Vt = (u16*)(ws + 201326592ull);      // overwrites Wt only after projections ran
  u16* P = (u16*)(ws + 0);                  // overwrites Qb/Kb only after scores ran

  dim3 blk(256, 1, 1);
  wt_transpose<<<dim3(32, 32, 1), blk, 0, stream>>>(Wq, Wqt);
  wt_transpose<<<dim3(32, 32, 1), blk, 0, stream>>>(Wk, Wkt);
  wt_transpose<<<dim3(32, 32, 1), blk, 0, stream>>>(Wv, Wvt);
  proj_gemm<<<dim3(8, 128, 1), blk, 0, stream>>>(query, Wqt, bq, Qb);
  proj_gemm<<<dim3(8, 128, 1), blk, 0, stream>>>(key_, Wkt, bk, Kb);
  proj_gemm<<<dim3(8, 128, 1), blk, 0, stream>>>(value, Wvt, bv, Vb);
  vt_transpose<<<dim3(32, 64, 8), blk, 0, stream>>>(Vb, Vt);
  scores_gemm<<<dim3(16, 16, 8), blk, 0, stream>>>(Qb, Kb, Sc);
  softmax_causal<<<dim3(2048, 8, 1), blk, 0, stream>>>(Sc, P);
  pv_gemm<<<dim3(8, 16, 8), blk, 0, stream>>>(P, Vt, out);
}

// Round 2
// 603.898 us; speedup vs baseline: 1.3206x; 1.3206x over previous
//
#include <hip/hip_runtime.h>

#define BB 8
#define SS 2048
#define DD 1024
#define BK 32          // K-tile (bf16 elems); unpadded LDS rows of 64 B (global_load_lds requirement)

typedef unsigned short u16;
typedef __bf16 bf16x8 __attribute__((ext_vector_type(8)));
typedef float f32x4 __attribute__((ext_vector_type(4)));

__device__ __forceinline__ u16 f2bf(float f) {
  unsigned int u = __builtin_bit_cast(unsigned int, f);
  u += 0x7fffu + ((u >> 16) & 1u);   // RNE
  return (u16)(u >> 16);
}

// async global->LDS, 16 B per lane, wave-uniform LDS base + lane*16
__device__ __forceinline__ void gl2lds16(const u16* g, u16* l) {
  __builtin_amdgcn_global_load_lds(
      (const __attribute__((address_space(1))) unsigned int*)g,
      (__attribute__((address_space(3))) unsigned int*)l, 16, 0, 0);
}

// Stage a 128x32 bf16 tile (unpadded, row-major) from global rows of stride `gstride`.
// Wave covers 16 rows per issue (4 lanes x 16B per 64B row); 2 issues per wave.
__device__ __forceinline__ void stage_tile(const u16* gbase, size_t gstride,
                                           u16* lds, int wave, int lane) {
#pragma unroll
  for (int r = 0; r < 2; r++) {
    int rowblk = r * 64 + wave * 16;
    int row = rowblk + (lane >> 2);
    int col = (lane & 3) * 8;
    gl2lds16(gbase + (size_t)row * gstride + col, lds + rowblk * BK);
  }
}

// ---------------- fp32 -> bf16 convert (8 elems/thread) ----------------
__global__ void convert_bf16(const float* __restrict__ x, u16* __restrict__ y) {
  size_t i = (size_t)blockIdx.x * 256 + threadIdx.x;
  const float4* s = (const float4*)x;
  float4 a = s[2 * i], b = s[2 * i + 1];
  uint4 p;
  p.x = (unsigned)f2bf(a.x) | ((unsigned)f2bf(a.y) << 16);
  p.y = (unsigned)f2bf(a.z) | ((unsigned)f2bf(a.w) << 16);
  p.z = (unsigned)f2bf(b.x) | ((unsigned)f2bf(b.y) << 16);
  p.w = (unsigned)f2bf(b.z) | ((unsigned)f2bf(b.w) << 16);
  ((uint4*)y)[i] = p;
}

// ---------------- transpose kernels ----------------
__global__ void wt_transpose(const float* __restrict__ W, u16* __restrict__ Wt) {
  __shared__ u16 t[32][33];
  int n0 = blockIdx.x * 32, k0 = blockIdx.y * 32;
  int tx = threadIdx.x & 31, ty = threadIdx.x >> 5;
#pragma unroll
  for (int i = 0; i < 32; i += 8)
    t[ty + i][tx] = f2bf(W[(size_t)(k0 + ty + i) * DD + n0 + tx]);
  __syncthreads();
#pragma unroll
  for (int i = 0; i < 32; i += 8)
    Wt[(size_t)(n0 + ty + i) * DD + k0 + tx] = t[tx][ty + i];
}

__global__ void vt_transpose(const u16* __restrict__ Vsd, u16* __restrict__ Vds) {
  __shared__ u16 t[32][33];
  int b = blockIdx.z;
  int d0 = blockIdx.x * 32, s0 = blockIdx.y * 32;
  const u16* src = Vsd + (size_t)b * SS * DD;
  u16* dst = Vds + (size_t)b * SS * DD;
  int tx = threadIdx.x & 31, ty = threadIdx.x >> 5;
#pragma unroll
  for (int i = 0; i < 32; i += 8)
    t[ty + i][tx] = src[(size_t)(s0 + ty + i) * DD + d0 + tx];
  __syncthreads();
#pragma unroll
  for (int i = 0; i < 32; i += 8)
    dst[(size_t)(d0 + ty + i) * SS + s0 + tx] = t[tx][ty + i];
}

// ---------------- MFMA tile body (unpadded stride BK=32) ----------------
__device__ __forceinline__ void mfma_tile(const u16* As, const u16* Bs, int wm, int wn,
                                          int quad, int l16, f32x4 (&acc)[4][4]) {
  bf16x8 a[4], b[4];
#pragma unroll
  for (int i = 0; i < 4; i++)
    a[i] = *reinterpret_cast<const bf16x8*>(&As[(wm + i * 16 + l16) * BK + quad * 8]);
#pragma unroll
  for (int j = 0; j < 4; j++)
    b[j] = *reinterpret_cast<const bf16x8*>(&Bs[(wn + j * 16 + l16) * BK + quad * 8]);
#pragma unroll
  for (int i = 0; i < 4; i++)
#pragma unroll
    for (int j = 0; j < 4; j++)
      acc[i][j] = __builtin_amdgcn_mfma_f32_16x16x32_bf16(a[i], b[j], acc[i][j], 0, 0, 0);
}

// ---------------- projection GEMM: Out[m][n] = bf16(Xb[m][:] @ Wt[n][:] + bias[n]) ----------------
__global__ void proj_gemm(const u16* __restrict__ Xb, const u16* __restrict__ Wt,
                          const float* __restrict__ bias, u16* __restrict__ Out) {
  __shared__ __align__(16) u16 As[128 * BK];
  __shared__ __align__(16) u16 Bs[128 * BK];
  int bn = blockIdx.x, bm = blockIdx.y;
  int m0 = bm * 128, n0 = bn * 128;
  int tid = threadIdx.x;
  int lane = tid & 63, wave = tid >> 6;
  int wm = (wave >> 1) * 64, wn = (wave & 1) * 64;
  int quad = lane >> 4, l16 = lane & 15;

  f32x4 acc[4][4];
  f32x4 z = {0.f, 0.f, 0.f, 0.f};
#pragma unroll
  for (int i = 0; i < 4; i++)
#pragma unroll
    for (int j = 0; j < 4; j++) acc[i][j] = z;

  for (int k0 = 0; k0 < DD; k0 += BK) {
    __syncthreads();
    stage_tile(Xb + (size_t)m0 * DD + k0, DD, As, wave, lane);
    stage_tile(Wt + (size_t)n0 * DD + k0, DD, Bs, wave, lane);
    __syncthreads();
    mfma_tile(As, Bs, wm, wn, quad, l16, acc);
  }
#pragma unroll
  for (int i = 0; i < 4; i++) {
#pragma unroll
    for (int r = 0; r < 4; r++) {
      int row = m0 + wm + i * 16 + quad * 4 + r;
#pragma unroll
      for (int j = 0; j < 4; j++) {
        int col = n0 + wn + j * 16 + l16;
        Out[(size_t)row * DD + col] = f2bf(acc[i][j][r] + bias[col]);
      }
    }
  }
}

// ---------------- causal scores GEMM: Sc[b][i][j] = (Q[i]·K[j])/32 for j<=i ----------------
__global__ void scores_gemm(const u16* __restrict__ Q, const u16* __restrict__ Kp,
                            float* __restrict__ Sc) {
  int bn = blockIdx.x, bm = blockIdx.y, b = blockIdx.z;
  if (bn > bm) return;  // fully masked tile
  __shared__ __align__(16) u16 As[128 * BK];
  __shared__ __align__(16) u16 Bs[128 * BK];
  const u16* Qb = Q + (size_t)b * SS * DD;
  const u16* Kb = Kp + (size_t)b * SS * DD;
  float* Sb = Sc + (size_t)b * SS * SS;
  int m0 = bm * 128, n0 = bn * 128;
  int tid = threadIdx.x;
  int lane = tid & 63, wave = tid >> 6;
  int wm = (wave >> 1) * 64, wn = (wave & 1) * 64;
  int quad = lane >> 4, l16 = lane & 15;

  f32x4 acc[4][4];
  f32x4 z = {0.f, 0.f, 0.f, 0.f};
#pragma unroll
  for (int i = 0; i < 4; i++)
#pragma unroll
    for (int j = 0; j < 4; j++) acc[i][j] = z;

  for (int k0 = 0; k0 < DD; k0 += BK) {
    __syncthreads();
    stage_tile(Qb + (size_t)m0 * DD + k0, DD, As, wave, lane);
    stage_tile(Kb + (size_t)n0 * DD + k0, DD, Bs, wave, lane);
    __syncthreads();
    mfma_tile(As, Bs, wm, wn, quad, l16, acc);
  }
#pragma unroll
  for (int i = 0; i < 4; i++) {
#pragma unroll
    for (int r = 0; r < 4; r++) {
      int gi = m0 + wm + i * 16 + quad * 4 + r;
#pragma unroll
      for (int j = 0; j < 4; j++) {
        int gj = n0 + wn + j * 16 + l16;
        if (gj <= gi) Sb[(size_t)gi * SS + gj] = acc[i][j][r] * 0.03125f;
      }
    }
  }
}

// ---------------- row softmax, causal, fp32 -> bf16 P ----------------
__global__ void softmax_causal(const float* __restrict__ Sc, u16* __restrict__ P) {
  int i = blockIdx.x, b = blockIdx.y;
  const float* srow = Sc + ((size_t)b * SS + i) * SS;
  u16* prow = P + ((size_t)b * SS + i) * SS;
  int n = i + 1;
  int tid = threadIdx.x;
  int lane = tid & 63, wave = tid >> 6;
  __shared__ float sm[4];
  __shared__ float ssum[4];

  float v[8];
  float mx = -3.0e38f;
#pragma unroll
  for (int u = 0; u < 8; u++) {
    int j = tid + u * 256;
    v[u] = (j < n) ? srow[j] : -3.0e38f;
    mx = fmaxf(mx, v[u]);
  }
#pragma unroll
  for (int off = 32; off > 0; off >>= 1) mx = fmaxf(mx, __shfl_down(mx, off, 64));
  if (lane == 0) sm[wave] = mx;
  __syncthreads();
  mx = fmaxf(fmaxf(sm[0], sm[1]), fmaxf(sm[2], sm[3]));

  float e[8];
  float sum = 0.f;
#pragma unroll
  for (int u = 0; u < 8; u++) {
    e[u] = __expf(v[u] - mx);
    sum += e[u];
  }
#pragma unroll
  for (int off = 32; off > 0; off >>= 1) sum += __shfl_down(sum, off, 64);
  if (lane == 0) ssum[wave] = sum;
  __syncthreads();
  sum = ssum[0] + ssum[1] + ssum[2] + ssum[3];
  float inv = 1.0f / sum;
#pragma unroll
  for (int u = 0; u < 8; u++) {
    int j = tid + u * 256;
    prow[j] = f2bf(e[u] * inv);
  }
}

// ---------------- PV GEMM: O[b][i][d] = P[b][i][:] @ Vt[d][:], causal K-loop skip ----------------
__global__ void pv_gemm(const u16* __restrict__ P, const u16* __restrict__ Vt,
                        float* __restrict__ O) {
  int bn = blockIdx.x, bm = blockIdx.y, b = blockIdx.z;
  __shared__ __align__(16) u16 As[128 * BK];
  __shared__ __align__(16) u16 Bs[128 * BK];
  const u16* Pb = P + (size_t)b * SS * SS;
  const u16* Vb = Vt + (size_t)b * SS * DD;  // [d][s]
  float* Ob = O + (size_t)b * SS * DD;
  int m0 = bm * 128, n0 = bn * 128;
  int tid = threadIdx.x;
  int lane = tid & 63, wave = tid >> 6;
  int wm = (wave >> 1) * 64, wn = (wave & 1) * 64;
  int quad = lane >> 4, l16 = lane & 15;

  f32x4 acc[4][4];
  f32x4 z = {0.f, 0.f, 0.f, 0.f};
#pragma unroll
  for (int i = 0; i < 4; i++)
#pragma unroll
    for (int j = 0; j < 4; j++) acc[i][j] = z;

  int kmax = (bm + 1) * 128;  // P[m][k]==0 for k>m
  for (int k0 = 0; k0 < kmax; k0 += BK) {
    __syncthreads();
    stage_tile(Pb + (size_t)m0 * SS + k0, SS, As, wave, lane);
    stage_tile(Vb + (size_t)n0 * SS + k0, SS, Bs, wave, lane);
    __syncthreads();
    mfma_tile(As, Bs, wm, wn, quad, l16, acc);
  }
#pragma unroll
  for (int i = 0; i < 4; i++) {
#pragma unroll
    for (int r = 0; r < 4; r++) {
      int row = m0 + wm + i * 16 + quad * 4 + r;
#pragma unroll
      for (int j = 0; j < 4; j++) {
        int col = n0 + wn + j * 16 + l16;
        Ob[(size_t)row * DD + col] = acc[i][j][r];
      }
    }
  }
}

extern "C" void kernel_launch(void* const* d_in, const int* in_sizes, int n_in,
                              void* d_out, int out_size, void* d_ws, size_t ws_size,
                              hipStream_t stream) {
  const float* query = (const float*)d_in[0];
  const float* key_ = (const float*)d_in[1];
  const float* value = (const float*)d_in[2];
  // d_in[3] = causal mask -- implemented structurally
  const float* Wq = (const float*)d_in[4];
  const float* bq = (const float*)d_in[5];
  const float* Wk = (const float*)d_in[6];
  const float* bk = (const float*)d_in[7];
  const float* Wv = (const float*)d_in[8];
  const float* bv = (const float*)d_in[9];
  float* out = (float*)d_out;
  char* ws = (char*)d_ws;

  const size_t MB = 1048576ull;
  // Workspace (peak 224 MB), stream-ordered lifetime aliasing:
  //  Xb  [0,32)    one shared bf16 activation buffer (conv->proj serially, x3)
  //  Vt  [0,32)    after Xb dead (post proj_v)
  //  Qb  [32,64)   Kb [64,96)  -> P [32,96) after scores
  //  Vb  [96,128)  Wt [128,134) -> Sc [96,224) after vt/projs
  u16* Xb  = (u16*)(ws + 0);
  u16* Vt  = (u16*)(ws + 0);
  u16* Qb  = (u16*)(ws + 32 * MB);
  u16* Kb  = (u16*)(ws + 64 * MB);
  u16* Vb  = (u16*)(ws + 96 * MB);
  u16* Wqt = (u16*)(ws + 128 * MB);
  u16* Wkt = (u16*)(ws + 130 * MB);
  u16* Wvt = (u16*)(ws + 132 * MB);
  float* Sc = (float*)(ws + 96 * MB);  // overwrites Vb/Wt after they are dead
  u16* P   = (u16*)(ws + 32 * MB);     // overwrites Qb/Kb after scores

  dim3 blk(256, 1, 1);
  wt_transpose<<<dim3(32, 32, 1), blk, 0, stream>>>(Wq, Wqt);
  wt_transpose<<<dim3(32, 32, 1), blk, 0, stream>>>(Wk, Wkt);
  wt_transpose<<<dim3(32, 32, 1), blk, 0, stream>>>(Wv, Wvt);

  convert_bf16<<<dim3(8192, 1, 1), blk, 0, stream>>>(query, Xb);
  proj_gemm<<<dim3(8, 128, 1), blk, 0, stream>>>(Xb, Wqt, bq, Qb);
  convert_bf16<<<dim3(8192, 1, 1), blk, 0, stream>>>(key_, Xb);
  proj_gemm<<<dim3(8, 128, 1), blk, 0, stream>>>(Xb, Wkt, bk, Kb);
  convert_bf16<<<dim3(8192, 1, 1), blk, 0, stream>>>(value, Xb);
  proj_gemm<<<dim3(8, 128, 1), blk, 0, stream>>>(Xb, Wvt, bv, Vb);

  vt_transpose<<<dim3(32, 64, 8), blk, 0, stream>>>(Vb, Vt);
  scores_gemm<<<dim3(16, 16, 8), blk, 0, stream>>>(Qb, Kb, Sc);
  softmax_causal<<<dim3(2048, 8, 1), blk, 0, stream>>>(Sc, P);
  pv_gemm<<<dim3(8, 16, 8), blk, 0, stream>>>(P, Vt, out);
}

// Round 3
// 565.956 us; speedup vs baseline: 1.4092x; 1.0670x over previous
//
#include <hip/hip_runtime.h>

#define BB 8
#define SS 2048
#define DD 1024
#define BK 32          // K-tile (bf16 elems); unpadded LDS rows of 64 B (global_load_lds requirement)

typedef unsigned short u16;
typedef __bf16 bf16x8 __attribute__((ext_vector_type(8)));
typedef float f32x4 __attribute__((ext_vector_type(4)));

__device__ __forceinline__ u16 f2bf(float f) {
  unsigned int u = __builtin_bit_cast(unsigned int, f);
  u += 0x7fffu + ((u >> 16) & 1u);   // RNE
  return (u16)(u >> 16);
}
__device__ __forceinline__ float bf2f(u16 h) {
  unsigned int u = ((unsigned int)h) << 16;
  return __builtin_bit_cast(float, u);
}

// async global->LDS, 16 B per lane, wave-uniform LDS base + lane*16
__device__ __forceinline__ void gl2lds16(const u16* g, u16* l) {
  __builtin_amdgcn_global_load_lds(
      (const __attribute__((address_space(1))) unsigned int*)g,
      (__attribute__((address_space(3))) unsigned int*)l, 16, 0, 0);
}

// Stage a 128x32 bf16 tile (unpadded, row-major) from global rows of stride gstride.
__device__ __forceinline__ void stage_tile(const u16* gbase, size_t gstride,
                                           u16* lds, int wave, int lane) {
#pragma unroll
  for (int r = 0; r < 2; r++) {
    int rowblk = r * 64 + wave * 16;
    int row = rowblk + (lane >> 2);
    int col = (lane & 3) * 8;
    gl2lds16(gbase + (size_t)row * gstride + col, lds + rowblk * BK);
  }
}

// ---------------- fp32 -> bf16 convert, fused over {q,k,v} via blockIdx.y ----------------
__global__ void convert_bf16(const float* __restrict__ q, const float* __restrict__ k,
                             const float* __restrict__ v, u16* __restrict__ Xall) {
  int z = blockIdx.y;
  const float* x = (z == 0) ? q : (z == 1) ? k : v;
  u16* y = Xall + (size_t)z * (BB * SS * DD);
  size_t i = (size_t)blockIdx.x * 256 + threadIdx.x;
  const float4* s = (const float4*)x;
  float4 a = s[2 * i], b = s[2 * i + 1];
  uint4 p;
  p.x = (unsigned)f2bf(a.x) | ((unsigned)f2bf(a.y) << 16);
  p.y = (unsigned)f2bf(a.z) | ((unsigned)f2bf(a.w) << 16);
  p.z = (unsigned)f2bf(b.x) | ((unsigned)f2bf(b.y) << 16);
  p.w = (unsigned)f2bf(b.z) | ((unsigned)f2bf(b.w) << 16);
  ((uint4*)y)[i] = p;
}

// ---------------- weight transpose, fused over {Wq,Wk,Wv} via blockIdx.z ----------------
__global__ void wt_transpose(const float* __restrict__ Wq, const float* __restrict__ Wk,
                             const float* __restrict__ Wv, u16* __restrict__ Wall) {
  __shared__ u16 t[32][33];
  int z = blockIdx.z & 3;
  const float* W = (z == 0) ? Wq : (z == 1) ? Wk : Wv;
  u16* Wt = Wall + (size_t)z * (DD * DD);
  int n0 = blockIdx.x * 32, k0 = blockIdx.y * 32;
  int tx = threadIdx.x & 31, ty = threadIdx.x >> 5;
#pragma unroll
  for (int i = 0; i < 32; i += 8)
    t[ty + i][tx] = f2bf(W[(size_t)(k0 + ty + i) * DD + n0 + tx]);
  __syncthreads();
#pragma unroll
  for (int i = 0; i < 32; i += 8)
    Wt[(size_t)(n0 + ty + i) * DD + k0 + tx] = t[tx][ty + i];
}

__global__ void vt_transpose(const u16* __restrict__ Vsd, u16* __restrict__ Vds) {
  __shared__ u16 t[32][33];
  int b = blockIdx.z;
  int d0 = blockIdx.x * 32, s0 = blockIdx.y * 32;
  const u16* src = Vsd + (size_t)b * SS * DD;
  u16* dst = Vds + (size_t)b * SS * DD;
  int tx = threadIdx.x & 31, ty = threadIdx.x >> 5;
#pragma unroll
  for (int i = 0; i < 32; i += 8)
    t[ty + i][tx] = src[(size_t)(s0 + ty + i) * DD + d0 + tx];
  __syncthreads();
#pragma unroll
  for (int i = 0; i < 32; i += 8)
    dst[(size_t)(d0 + ty + i) * SS + s0 + tx] = t[tx][ty + i];
}

// ---------------- MFMA tile body (unpadded stride BK=32) ----------------
__device__ __forceinline__ void mfma_tile(const u16* As, const u16* Bs, int wm, int wn,
                                          int quad, int l16, f32x4 (&acc)[4][4]) {
  bf16x8 a[4], b[4];
#pragma unroll
  for (int i = 0; i < 4; i++)
    a[i] = *reinterpret_cast<const bf16x8*>(&As[(wm + i * 16 + l16) * BK + quad * 8]);
#pragma unroll
  for (int j = 0; j < 4; j++)
    b[j] = *reinterpret_cast<const bf16x8*>(&Bs[(wn + j * 16 + l16) * BK + quad * 8]);
#pragma unroll
  for (int i = 0; i < 4; i++)
#pragma unroll
    for (int j = 0; j < 4; j++)
      acc[i][j] = __builtin_amdgcn_mfma_f32_16x16x32_bf16(a[i], b[j], acc[i][j], 0, 0, 0);
}

// ---------------- fused projection GEMM over {q,k,v} via blockIdx.z ----------------
__global__ void proj_gemm(const u16* __restrict__ Xall, const u16* __restrict__ Wall,
                          const float* __restrict__ bq, const float* __restrict__ bk,
                          const float* __restrict__ bv, u16* __restrict__ QKV) {
  __shared__ __align__(16) u16 As[128 * BK];
  __shared__ __align__(16) u16 Bs[128 * BK];
  int z = blockIdx.z;
  const u16* Xb = Xall + (size_t)z * (BB * SS * DD);
  const u16* Wt = Wall + (size_t)z * (DD * DD);
  const float* bias = (z == 0) ? bq : (z == 1) ? bk : bv;
  u16* Out = QKV + (size_t)z * (BB * SS * DD);
  int bn = blockIdx.x, bm = blockIdx.y;
  int m0 = bm * 128, n0 = bn * 128;
  int tid = threadIdx.x;
  int lane = tid & 63, wave = tid >> 6;
  int wm = (wave >> 1) * 64, wn = (wave & 1) * 64;
  int quad = lane >> 4, l16 = lane & 15;

  f32x4 acc[4][4];
  f32x4 zz = {0.f, 0.f, 0.f, 0.f};
#pragma unroll
  for (int i = 0; i < 4; i++)
#pragma unroll
    for (int j = 0; j < 4; j++) acc[i][j] = zz;

  for (int k0 = 0; k0 < DD; k0 += BK) {
    __syncthreads();
    stage_tile(Xb + (size_t)m0 * DD + k0, DD, As, wave, lane);
    stage_tile(Wt + (size_t)n0 * DD + k0, DD, Bs, wave, lane);
    __syncthreads();
    mfma_tile(As, Bs, wm, wn, quad, l16, acc);
  }
#pragma unroll
  for (int i = 0; i < 4; i++) {
#pragma unroll
    for (int r = 0; r < 4; r++) {
      int row = m0 + wm + i * 16 + quad * 4 + r;
#pragma unroll
      for (int j = 0; j < 4; j++) {
        int col = n0 + wn + j * 16 + l16;
        Out[(size_t)row * DD + col] = f2bf(acc[i][j][r] + bias[col]);
      }
    }
  }
}

// ---------------- causal scores GEMM, triangular-compacted grid ----------------
// blockIdx.x = linear lower-triangle tile id (136), blockIdx.y = batch.
// Sc[b][i][j] = bf16((Q[i]·K[j])/32) for j<=i.
__global__ void scores_gemm(const u16* __restrict__ Q, const u16* __restrict__ Kp,
                            u16* __restrict__ Sc) {
  __shared__ __align__(16) u16 As[128 * BK];
  __shared__ __align__(16) u16 Bs[128 * BK];
  int t = blockIdx.x, b = blockIdx.y;
  int bm = (int)((sqrtf(8.f * t + 1.f) - 1.f) * 0.5f);
  while ((bm + 1) * (bm + 2) / 2 <= t) bm++;
  while (bm * (bm + 1) / 2 > t) bm--;
  int bn = t - bm * (bm + 1) / 2;

  const u16* Qb = Q + (size_t)b * SS * DD;
  const u16* Kb = Kp + (size_t)b * SS * DD;
  u16* Sb = Sc + (size_t)b * SS * SS;
  int m0 = bm * 128, n0 = bn * 128;
  int tid = threadIdx.x;
  int lane = tid & 63, wave = tid >> 6;
  int wm = (wave >> 1) * 64, wn = (wave & 1) * 64;
  int quad = lane >> 4, l16 = lane & 15;

  f32x4 acc[4][4];
  f32x4 z = {0.f, 0.f, 0.f, 0.f};
#pragma unroll
  for (int i = 0; i < 4; i++)
#pragma unroll
    for (int j = 0; j < 4; j++) acc[i][j] = z;

  for (int k0 = 0; k0 < DD; k0 += BK) {
    __syncthreads();
    stage_tile(Qb + (size_t)m0 * DD + k0, DD, As, wave, lane);
    stage_tile(Kb + (size_t)n0 * DD + k0, DD, Bs, wave, lane);
    __syncthreads();
    mfma_tile(As, Bs, wm, wn, quad, l16, acc);
  }
#pragma unroll
  for (int i = 0; i < 4; i++) {
#pragma unroll
    for (int r = 0; r < 4; r++) {
      int gi = m0 + wm + i * 16 + quad * 4 + r;
#pragma unroll
      for (int j = 0; j < 4; j++) {
        int gj = n0 + wn + j * 16 + l16;
        if (gj <= gi) Sb[(size_t)gi * SS + gj] = f2bf(acc[i][j][r] * 0.03125f);
      }
    }
  }
}

// ---------------- row softmax, causal, bf16 in -> bf16 P, vectorized ----------------
__global__ void softmax_causal(const u16* __restrict__ Sc, u16* __restrict__ P) {
  int i = blockIdx.x, b = blockIdx.y;
  const u16* srow = Sc + ((size_t)b * SS + i) * SS;
  u16* prow = P + ((size_t)b * SS + i) * SS;
  int n = i + 1;
  int tid = threadIdx.x;
  int lane = tid & 63, wave = tid >> 6;
  __shared__ float sm[4];
  __shared__ float ssum[4];

  uint4 raw = ((const uint4*)srow)[tid];  // 8 bf16, elems j = tid*8 + e
  unsigned w[4] = {raw.x, raw.y, raw.z, raw.w};
  int j0 = tid * 8;
  float v[8];
  float mx = -3.0e38f;
#pragma unroll
  for (int u = 0; u < 8; u++) {
    u16 h = (u16)((w[u >> 1] >> ((u & 1) * 16)) & 0xffffu);
    v[u] = (j0 + u < n) ? bf2f(h) : -3.0e38f;
    mx = fmaxf(mx, v[u]);
  }
#pragma unroll
  for (int off = 32; off > 0; off >>= 1) mx = fmaxf(mx, __shfl_down(mx, off, 64));
  if (lane == 0) sm[wave] = mx;
  __syncthreads();
  mx = fmaxf(fmaxf(sm[0], sm[1]), fmaxf(sm[2], sm[3]));

  float e[8];
  float sum = 0.f;
#pragma unroll
  for (int u = 0; u < 8; u++) {
    e[u] = __expf(v[u] - mx);  // masked -> exp(-inf) -> 0
    sum += e[u];
  }
#pragma unroll
  for (int off = 32; off > 0; off >>= 1) sum += __shfl_down(sum, off, 64);
  if (lane == 0) ssum[wave] = sum;
  __syncthreads();
  sum = ssum[0] + ssum[1] + ssum[2] + ssum[3];
  float inv = 1.0f / sum;
  uint4 o;
  unsigned* ow = (unsigned*)&o;
#pragma unroll
  for (int u = 0; u < 4; u++) {
    u16 lo = f2bf(e[2 * u] * inv);
    u16 hi = f2bf(e[2 * u + 1] * inv);
    ow[u] = (unsigned)lo | ((unsigned)hi << 16);
  }
  ((uint4*)prow)[tid] = o;
}

// ---------------- PV GEMM, paired m-tiles for uniform work ----------------
// blockIdx = (d-tile 0..7, pair 0..7, batch). Each block does m-tiles {pair, 15-pair}:
// K-iters (pair+1 + 16-pair)*4 = 68, uniform across all 512 blocks.
__global__ void pv_gemm(const u16* __restrict__ P, const u16* __restrict__ Vt,
                        float* __restrict__ O) {
  __shared__ __align__(16) u16 As[128 * BK];
  __shared__ __align__(16) u16 Bs[128 * BK];
  int bn = blockIdx.x, pair = blockIdx.y, b = blockIdx.z;
  const u16* Pb = P + (size_t)b * SS * SS;
  const u16* Vb = Vt + (size_t)b * SS * DD;  // [d][s]
  float* Ob = O + (size_t)b * SS * DD;
  int n0 = bn * 128;
  int tid = threadIdx.x;
  int lane = tid & 63, wave = tid >> 6;
  int wm = (wave >> 1) * 64, wn = (wave & 1) * 64;
  int quad = lane >> 4, l16 = lane & 15;

#pragma unroll
  for (int phase = 0; phase < 2; phase++) {
    int bm = phase ? (15 - pair) : pair;
    int m0 = bm * 128;
    f32x4 acc[4][4];
    f32x4 z = {0.f, 0.f, 0.f, 0.f};
#pragma unroll
    for (int i = 0; i < 4; i++)
#pragma unroll
      for (int j = 0; j < 4; j++) acc[i][j] = z;

    int kmax = (bm + 1) * 128;  // P[m][k]==0 for k>m
    for (int k0 = 0; k0 < kmax; k0 += BK) {
      __syncthreads();
      stage_tile(Pb + (size_t)m0 * SS + k0, SS, As, wave, lane);
      stage_tile(Vb + (size_t)n0 * SS + k0, SS, Bs, wave, lane);
      __syncthreads();
      mfma_tile(As, Bs, wm, wn, quad, l16, acc);
    }
#pragma unroll
    for (int i = 0; i < 4; i++) {
#pragma unroll
      for (int r = 0; r < 4; r++) {
        int row = m0 + wm + i * 16 + quad * 4 + r;
#pragma unroll
        for (int j = 0; j < 4; j++) {
          int col = n0 + wn + j * 16 + l16;
          Ob[(size_t)row * DD + col] = acc[i][j][r];
        }
      }
    }
  }
}

extern "C" void kernel_launch(void* const* d_in, const int* in_sizes, int n_in,
                              void* d_out, int out_size, void* d_ws, size_t ws_size,
                              hipStream_t stream) {
  const float* query = (const float*)d_in[0];
  const float* key_ = (const float*)d_in[1];
  const float* value = (const float*)d_in[2];
  // d_in[3] = causal mask -- implemented structurally
  const float* Wq = (const float*)d_in[4];
  const float* bq = (const float*)d_in[5];
  const float* Wk = (const float*)d_in[6];
  const float* bk = (const float*)d_in[7];
  const float* Wv = (const float*)d_in[8];
  const float* bv = (const float*)d_in[9];
  float* out = (float*)d_out;
  char* ws = (char*)d_ws;

  const size_t MB = 1048576ull;
  // Workspace (peak 198 MB), stream-ordered lifetime aliasing:
  //  Xall [0,96)   3x bf16 activations (dead after proj)
  //  QKV  [96,192) Qb/Kb/Vb bf16 (dead after scores / vt)
  //  Wall [192,198) 3x Wt bf16 (dead after proj)
  //  Vt   [0,32)   over dead Xall
  //  Sc   [32,96)  bf16 64 MB, over dead Xall
  //  P    [96,160) bf16 64 MB, over dead Qb/Kb
  u16* Xall = (u16*)(ws + 0);
  u16* QKV  = (u16*)(ws + 96 * MB);
  u16* Qb   = (u16*)(ws + 96 * MB);
  u16* Kb   = (u16*)(ws + 128 * MB);
  u16* Vb   = (u16*)(ws + 160 * MB);
  u16* Wall = (u16*)(ws + 192 * MB);
  u16* Vt   = (u16*)(ws + 0);
  u16* Sc   = (u16*)(ws + 32 * MB);
  u16* P    = (u16*)(ws + 96 * MB);

  dim3 blk(256, 1, 1);
  wt_transpose<<<dim3(32, 32, 3), blk, 0, stream>>>(Wq, Wk, Wv, Wall);
  convert_bf16<<<dim3(8192, 3, 1), blk, 0, stream>>>(query, key_, value, Xall);
  proj_gemm<<<dim3(8, 128, 3), blk, 0, stream>>>(Xall, Wall, bq, bk, bv, QKV);
  vt_transpose<<<dim3(32, 64, 8), blk, 0, stream>>>(Vb, Vt);
  scores_gemm<<<dim3(136, 8, 1), blk, 0, stream>>>(Qb, Kb, Sc);
  softmax_causal<<<dim3(2048, 8, 1), blk, 0, stream>>>(Sc, P);
  pv_gemm<<<dim3(8, 8, 8), blk, 0, stream>>>(P, Vt, out);
}

// Round 4
// 521.435 us; speedup vs baseline: 1.5295x; 1.0854x over previous
//
#include <hip/hip_runtime.h>

#define BB 8
#define SS 2048
#define DD 1024
#define BK 32          // K-tile (bf16 elems); unpadded LDS rows of 64 B (global_load_lds requirement)

typedef unsigned short u16;
typedef __bf16 bf16x8 __attribute__((ext_vector_type(8)));
typedef float f32x4 __attribute__((ext_vector_type(4)));

__device__ __forceinline__ u16 f2bf(float f) {
  unsigned int u = __builtin_bit_cast(unsigned int, f);
  u += 0x7fffu + ((u >> 16) & 1u);   // RNE
  return (u16)(u >> 16);
}
__device__ __forceinline__ float bf2f(u16 h) {
  unsigned int u = ((unsigned int)h) << 16;
  return __builtin_bit_cast(float, u);
}

// async global->LDS, 16 B per lane, wave-uniform LDS base + lane*16
__device__ __forceinline__ void gl2lds16(const u16* g, u16* l) {
  __builtin_amdgcn_global_load_lds(
      (const __attribute__((address_space(1))) unsigned int*)g,
      (__attribute__((address_space(3))) unsigned int*)l, 16, 0, 0);
}

// Stage a 128x32 bf16 tile (unpadded, row-major) from global rows of stride gstride.
__device__ __forceinline__ void stage_tile(const u16* gbase, size_t gstride,
                                           u16* lds, int wave, int lane) {
#pragma unroll
  for (int r = 0; r < 2; r++) {
    int rowblk = r * 64 + wave * 16;
    int row = rowblk + (lane >> 2);
    int col = (lane & 3) * 8;
    gl2lds16(gbase + (size_t)row * gstride + col, lds + rowblk * BK);
  }
}

// ---------------- fp32 -> bf16 convert, fused over {q,k,v} via blockIdx.y ----------------
__global__ void convert_bf16(const float* __restrict__ q, const float* __restrict__ k,
                             const float* __restrict__ v, u16* __restrict__ Xall) {
  int z = blockIdx.y;
  const float* x = (z == 0) ? q : (z == 1) ? k : v;
  u16* y = Xall + (size_t)z * (BB * SS * DD);
  size_t i = (size_t)blockIdx.x * 256 + threadIdx.x;
  const float4* s = (const float4*)x;
  float4 a = s[2 * i], b = s[2 * i + 1];
  uint4 p;
  p.x = (unsigned)f2bf(a.x) | ((unsigned)f2bf(a.y) << 16);
  p.y = (unsigned)f2bf(a.z) | ((unsigned)f2bf(a.w) << 16);
  p.z = (unsigned)f2bf(b.x) | ((unsigned)f2bf(b.y) << 16);
  p.w = (unsigned)f2bf(b.z) | ((unsigned)f2bf(b.w) << 16);
  ((uint4*)y)[i] = p;
}

// ---------------- weight transpose, fused over {Wq,Wk,Wv} via blockIdx.z ----------------
__global__ void wt_transpose(const float* __restrict__ Wq, const float* __restrict__ Wk,
                             const float* __restrict__ Wv, u16* __restrict__ Wall) {
  __shared__ u16 t[32][33];
  int z = blockIdx.z & 3;
  const float* W = (z == 0) ? Wq : (z == 1) ? Wk : Wv;
  u16* Wt = Wall + (size_t)z * (DD * DD);
  int n0 = blockIdx.x * 32, k0 = blockIdx.y * 32;
  int tx = threadIdx.x & 31, ty = threadIdx.x >> 5;
#pragma unroll
  for (int i = 0; i < 32; i += 8)
    t[ty + i][tx] = f2bf(W[(size_t)(k0 + ty + i) * DD + n0 + tx]);
  __syncthreads();
#pragma unroll
  for (int i = 0; i < 32; i += 8)
    Wt[(size_t)(n0 + ty + i) * DD + k0 + tx] = t[tx][ty + i];
}

__global__ void vt_transpose(const u16* __restrict__ Vsd, u16* __restrict__ Vds) {
  __shared__ u16 t[32][33];
  int b = blockIdx.z;
  int d0 = blockIdx.x * 32, s0 = blockIdx.y * 32;
  const u16* src = Vsd + (size_t)b * SS * DD;
  u16* dst = Vds + (size_t)b * SS * DD;
  int tx = threadIdx.x & 31, ty = threadIdx.x >> 5;
#pragma unroll
  for (int i = 0; i < 32; i += 8)
    t[ty + i][tx] = src[(size_t)(s0 + ty + i) * DD + d0 + tx];
  __syncthreads();
#pragma unroll
  for (int i = 0; i < 32; i += 8)
    dst[(size_t)(d0 + ty + i) * SS + s0 + tx] = t[tx][ty + i];
}

// ---------------- MFMA tile body, 128x128 (unpadded stride BK=32) ----------------
__device__ __forceinline__ void mfma_tile(const u16* As, const u16* Bs, int wm, int wn,
                                          int quad, int l16, f32x4 (&acc)[4][4]) {
  bf16x8 a[4], b[4];
#pragma unroll
  for (int i = 0; i < 4; i++)
    a[i] = *reinterpret_cast<const bf16x8*>(&As[(wm + i * 16 + l16) * BK + quad * 8]);
#pragma unroll
  for (int j = 0; j < 4; j++)
    b[j] = *reinterpret_cast<const bf16x8*>(&Bs[(wn + j * 16 + l16) * BK + quad * 8]);
#pragma unroll
  for (int i = 0; i < 4; i++)
#pragma unroll
    for (int j = 0; j < 4; j++)
      acc[i][j] = __builtin_amdgcn_mfma_f32_16x16x32_bf16(a[i], b[j], acc[i][j], 0, 0, 0);
}

// ---------------- fused projection GEMM, XCD-swizzled 1D grid ----------------
// id in [0,3072): z = id>>10; rem = id&1023; r = rem&7 (XCD residue); j = rem>>3;
// bn = j&7, bm = (j>>3)*8 + r  => blocks co-resident on one XCD share the X row-panel,
// and W (2 MB) stays resident in that XCD's L2 across all its bm.
__global__ void proj_gemm(const u16* __restrict__ Xall, const u16* __restrict__ Wall,
                          const float* __restrict__ bq, const float* __restrict__ bk,
                          const float* __restrict__ bv, u16* __restrict__ QKV) {
  __shared__ __align__(16) u16 As[128 * BK];
  __shared__ __align__(16) u16 Bs[128 * BK];
  int id = blockIdx.x;
  int z = id >> 10, rem = id & 1023;
  int r = rem & 7, j = rem >> 3;
  int bn = j & 7, bm = ((j >> 3) << 3) | r;
  const u16* Xb = Xall + (size_t)z * (BB * SS * DD);
  const u16* Wt = Wall + (size_t)z * (DD * DD);
  const float* bias = (z == 0) ? bq : (z == 1) ? bk : bv;
  u16* Out = QKV + (size_t)z * (BB * SS * DD);
  int m0 = bm * 128, n0 = bn * 128;
  int tid = threadIdx.x;
  int lane = tid & 63, wave = tid >> 6;
  int wm = (wave >> 1) * 64, wn = (wave & 1) * 64;
  int quad = lane >> 4, l16 = lane & 15;

  f32x4 acc[4][4];
  f32x4 zz = {0.f, 0.f, 0.f, 0.f};
#pragma unroll
  for (int i = 0; i < 4; i++)
#pragma unroll
    for (int jj = 0; jj < 4; jj++) acc[i][jj] = zz;

  for (int k0 = 0; k0 < DD; k0 += BK) {
    __syncthreads();
    stage_tile(Xb + (size_t)m0 * DD + k0, DD, As, wave, lane);
    stage_tile(Wt + (size_t)n0 * DD + k0, DD, Bs, wave, lane);
    __syncthreads();
    mfma_tile(As, Bs, wm, wn, quad, l16, acc);
  }
#pragma unroll
  for (int i = 0; i < 4; i++) {
#pragma unroll
    for (int rr = 0; rr < 4; rr++) {
      int row = m0 + wm + i * 16 + quad * 4 + rr;
#pragma unroll
      for (int jj = 0; jj < 4; jj++) {
        int col = n0 + wn + jj * 16 + l16;
        Out[(size_t)row * DD + col] = f2bf(acc[i][jj][rr] + bias[col]);
      }
    }
  }
}

// ---------------- causal scores GEMM, triangular-compacted, batch-per-XCD ----------------
// id in [0,1088): b = id&7 (XCD residue = batch), t = id>>3 (triangular tile id).
__global__ void scores_gemm(const u16* __restrict__ Q, const u16* __restrict__ Kp,
                            u16* __restrict__ Sc) {
  __shared__ __align__(16) u16 As[128 * BK];
  __shared__ __align__(16) u16 Bs[128 * BK];
  int id = blockIdx.x;
  int b = id & 7, t = id >> 3;
  int bm = (int)((sqrtf(8.f * t + 1.f) - 1.f) * 0.5f);
  while ((bm + 1) * (bm + 2) / 2 <= t) bm++;
  while (bm * (bm + 1) / 2 > t) bm--;
  int bn = t - bm * (bm + 1) / 2;

  const u16* Qb = Q + (size_t)b * SS * DD;
  const u16* Kb = Kp + (size_t)b * SS * DD;
  u16* Sb = Sc + (size_t)b * SS * SS;
  int m0 = bm * 128, n0 = bn * 128;
  int tid = threadIdx.x;
  int lane = tid & 63, wave = tid >> 6;
  int wm = (wave >> 1) * 64, wn = (wave & 1) * 64;
  int quad = lane >> 4, l16 = lane & 15;

  f32x4 acc[4][4];
  f32x4 z = {0.f, 0.f, 0.f, 0.f};
#pragma unroll
  for (int i = 0; i < 4; i++)
#pragma unroll
    for (int jj = 0; jj < 4; jj++) acc[i][jj] = z;

  for (int k0 = 0; k0 < DD; k0 += BK) {
    __syncthreads();
    stage_tile(Qb + (size_t)m0 * DD + k0, DD, As, wave, lane);
    stage_tile(Kb + (size_t)n0 * DD + k0, DD, Bs, wave, lane);
    __syncthreads();
    mfma_tile(As, Bs, wm, wn, quad, l16, acc);
  }
#pragma unroll
  for (int i = 0; i < 4; i++) {
#pragma unroll
    for (int rr = 0; rr < 4; rr++) {
      int gi = m0 + wm + i * 16 + quad * 4 + rr;
#pragma unroll
      for (int jj = 0; jj < 4; jj++) {
        int gj = n0 + wn + jj * 16 + l16;
        if (gj <= gi) Sb[(size_t)gi * SS + gj] = f2bf(acc[i][jj][rr] * 0.03125f);
      }
    }
  }
}

// ---------------- row softmax, causal-truncated to roundup(i+1,128) ----------------
__global__ void softmax_causal(const u16* __restrict__ Sc, u16* __restrict__ P) {
  int i = blockIdx.x, b = blockIdx.y;
  const u16* srow = Sc + ((size_t)b * SS + i) * SS;
  u16* prow = P + ((size_t)b * SS + i) * SS;
  int n = i + 1;
  int nceil = ((i >> 7) + 1) << 7;  // pv reads only [0, roundup64(n)) ⊆ [0, nceil)
  int tid = threadIdx.x;
  int lane = tid & 63, wave = tid >> 6;
  __shared__ float sm[4];
  __shared__ float ssum[4];

  int j0 = tid * 8;
  bool act = j0 < nceil;
  float v[8];
  float mx = -3.0e38f;
  if (act) {
    uint4 raw = ((const uint4*)srow)[tid];
    unsigned w[4] = {raw.x, raw.y, raw.z, raw.w};
#pragma unroll
    for (int u = 0; u < 8; u++) {
      u16 h = (u16)((w[u >> 1] >> ((u & 1) * 16)) & 0xffffu);
      v[u] = (j0 + u < n) ? bf2f(h) : -3.0e38f;
      mx = fmaxf(mx, v[u]);
    }
  } else {
#pragma unroll
    for (int u = 0; u < 8; u++) v[u] = -3.0e38f;
  }
#pragma unroll
  for (int off = 32; off > 0; off >>= 1) mx = fmaxf(mx, __shfl_down(mx, off, 64));
  if (lane == 0) sm[wave] = mx;
  __syncthreads();
  mx = fmaxf(fmaxf(sm[0], sm[1]), fmaxf(sm[2], sm[3]));

  float e[8];
  float sum = 0.f;
#pragma unroll
  for (int u = 0; u < 8; u++) {
    e[u] = __expf(v[u] - mx);  // masked -> 0
    sum += e[u];
  }
#pragma unroll
  for (int off = 32; off > 0; off >>= 1) sum += __shfl_down(sum, off, 64);
  if (lane == 0) ssum[wave] = sum;
  __syncthreads();
  sum = ssum[0] + ssum[1] + ssum[2] + ssum[3];
  float inv = 1.0f / sum;
  if (act) {
    uint4 o;
    unsigned* ow = (unsigned*)&o;
#pragma unroll
    for (int u = 0; u < 4; u++) {
      u16 lo = f2bf(e[2 * u] * inv);
      u16 hi = f2bf(e[2 * u + 1] * inv);
      ow[u] = (unsigned)lo | ((unsigned)hi << 16);
    }
    ((uint4*)prow)[tid] = o;
  }
}

// ---------------- PV GEMM, 64x128 tiles, paired m-tiles, V-slice-per-XCD ----------------
// id in [0,1024): bn = id&7 (XCD residue -> each XCD keeps its 128-row Vt slice in L2),
// q = (id>>3)&15 (pair), b = id>>7. Phases bm = q and 31-q: K-iters 2(q+1)+2(32-q)=66 uniform.
__global__ void pv_gemm(const u16* __restrict__ P, const u16* __restrict__ Vt,
                        float* __restrict__ O) {
  __shared__ __align__(16) u16 As[64 * BK];
  __shared__ __align__(16) u16 Bs[128 * BK];
  int id = blockIdx.x;
  int bn = id & 7, q = (id >> 3) & 15, b = id >> 7;
  const u16* Pb = P + (size_t)b * SS * SS;
  const u16* Vb = Vt + (size_t)b * SS * DD;  // [d][s]
  float* Ob = O + (size_t)b * SS * DD;
  int n0 = bn * 128;
  int tid = threadIdx.x;
  int lane = tid & 63, wave = tid >> 6;
  int wn = wave * 32;
  int quad = lane >> 4, l16 = lane & 15;

#pragma unroll
  for (int phase = 0; phase < 2; phase++) {
    int bm = phase ? (31 - q) : q;
    int m0 = bm * 64;
    f32x4 acc[4][2];
    f32x4 z = {0.f, 0.f, 0.f, 0.f};
#pragma unroll
    for (int i = 0; i < 4; i++)
#pragma unroll
      for (int jj = 0; jj < 2; jj++) acc[i][jj] = z;

    int kmax = (bm + 1) * 64;  // P[m][k]==0 for k>m; rows here have m <= m0+63
    for (int k0 = 0; k0 < kmax; k0 += BK) {
      __syncthreads();
      {  // A: 64 rows x 32 cols, one issue per wave (16 rows each)
        int row = wave * 16 + (lane >> 2);
        int col = (lane & 3) * 8;
        gl2lds16(Pb + (size_t)(m0 + row) * SS + k0 + col, As + wave * 16 * BK);
      }
      stage_tile(Vb + (size_t)n0 * SS + k0, SS, Bs, wave, lane);
      __syncthreads();
      bf16x8 a[4], bb[2];
#pragma unroll
      for (int i = 0; i < 4; i++)
        a[i] = *reinterpret_cast<const bf16x8*>(&As[(i * 16 + l16) * BK + quad * 8]);
#pragma unroll
      for (int jj = 0; jj < 2; jj++)
        bb[jj] = *reinterpret_cast<const bf16x8*>(&Bs[(wn + jj * 16 + l16) * BK + quad * 8]);
#pragma unroll
      for (int i = 0; i < 4; i++)
#pragma unroll
        for (int jj = 0; jj < 2; jj++)
          acc[i][jj] = __builtin_amdgcn_mfma_f32_16x16x32_bf16(a[i], bb[jj], acc[i][jj], 0, 0, 0);
    }
#pragma unroll
    for (int i = 0; i < 4; i++) {
#pragma unroll
      for (int rr = 0; rr < 4; rr++) {
        int row = m0 + i * 16 + quad * 4 + rr;
#pragma unroll
        for (int jj = 0; jj < 2; jj++) {
          int col = n0 + wn + jj * 16 + l16;
          Ob[(size_t)row * DD + col] = acc[i][jj][rr];
        }
      }
    }
  }
}

extern "C" void kernel_launch(void* const* d_in, const int* in_sizes, int n_in,
                              void* d_out, int out_size, void* d_ws, size_t ws_size,
                              hipStream_t stream) {
  const float* query = (const float*)d_in[0];
  const float* key_ = (const float*)d_in[1];
  const float* value = (const float*)d_in[2];
  // d_in[3] = causal mask -- implemented structurally
  const float* Wq = (const float*)d_in[4];
  const float* bq = (const float*)d_in[5];
  const float* Wk = (const float*)d_in[6];
  const float* bk = (const float*)d_in[7];
  const float* Wv = (const float*)d_in[8];
  const float* bv = (const float*)d_in[9];
  float* out = (float*)d_out;
  char* ws = (char*)d_ws;

  const size_t MB = 1048576ull;
  // Workspace (peak 198 MB), stream-ordered lifetime aliasing:
  //  Xall [0,96)    3x bf16 activations (dead after proj)
  //  QKV  [96,192)  Qb/Kb/Vb bf16
  //  Wall [192,198) 3x Wt bf16
  //  Vt   [0,32)    over dead Xall
  //  Sc   [32,96)   bf16 64 MB, over dead Xall
  //  P    [96,160)  bf16 64 MB, over dead Qb/Kb
  u16* Xall = (u16*)(ws + 0);
  u16* QKV  = (u16*)(ws + 96 * MB);
  u16* Qb   = (u16*)(ws + 96 * MB);
  u16* Kb   = (u16*)(ws + 128 * MB);
  u16* Vb   = (u16*)(ws + 160 * MB);
  u16* Wall = (u16*)(ws + 192 * MB);
  u16* Vt   = (u16*)(ws + 0);
  u16* Sc   = (u16*)(ws + 32 * MB);
  u16* P    = (u16*)(ws + 96 * MB);

  dim3 blk(256, 1, 1);
  wt_transpose<<<dim3(32, 32, 3), blk, 0, stream>>>(Wq, Wk, Wv, Wall);
  convert_bf16<<<dim3(8192, 3, 1), blk, 0, stream>>>(query, key_, value, Xall);
  proj_gemm<<<dim3(3072, 1, 1), blk, 0, stream>>>(Xall, Wall, bq, bk, bv, QKV);
  vt_transpose<<<dim3(32, 64, 8), blk, 0, stream>>>(Vb, Vt);
  scores_gemm<<<dim3(1088, 1, 1), blk, 0, stream>>>(Qb, Kb, Sc);
  softmax_causal<<<dim3(2048, 8, 1), blk, 0, stream>>>(Sc, P);
  pv_gemm<<<dim3(1024, 1, 1), blk, 0, stream>>>(P, Vt, out);
}

// Round 5
// 477.634 us; speedup vs baseline: 1.6697x; 1.0917x over previous
//
#include <hip/hip_runtime.h>

#define BB 8
#define SS 2048
#define DD 1024
#define BK 32          // LDS sub-tile K width (bf16); rows of 64 B (global_load_lds unit)
#define TSZ (128 * BK) // elems per 128-row sub-tile

typedef unsigned short u16;
typedef __bf16 bf16x8 __attribute__((ext_vector_type(8)));
typedef float f32x4 __attribute__((ext_vector_type(4)));

__device__ __forceinline__ u16 f2bf(float f) {
  unsigned int u = __builtin_bit_cast(unsigned int, f);
  u += 0x7fffu + ((u >> 16) & 1u);   // RNE
  return (u16)(u >> 16);
}
__device__ __forceinline__ float bf2f(u16 h) {
  unsigned int u = ((unsigned int)h) << 16;
  return __builtin_bit_cast(float, u);
}

// async global->LDS, 16 B per lane, wave-uniform LDS base + lane*16
__device__ __forceinline__ void gl2lds16(const u16* g, u16* l) {
  __builtin_amdgcn_global_load_lds(
      (const __attribute__((address_space(1))) unsigned int*)g,
      (__attribute__((address_space(3))) unsigned int*)l, 16, 0, 0);
}

// Stage a 128x32 bf16 sub-tile (unpadded row-major) from global rows of stride gstride.
__device__ __forceinline__ void stage_tile(const u16* gbase, size_t gstride,
                                           u16* lds, int wave, int lane) {
#pragma unroll
  for (int r = 0; r < 2; r++) {
    int rowblk = r * 64 + wave * 16;
    int row = rowblk + (lane >> 2);
    int col = (lane & 3) * 8;
    gl2lds16(gbase + (size_t)row * gstride + col, lds + rowblk * BK);
  }
}

// ---------------- MFMA body for one 128x128 x BK=32 sub-tile ----------------
__device__ __forceinline__ void mfma_tile(const u16* As, const u16* Bs, int wm, int wn,
                                          int quad, int l16, f32x4 (&acc)[4][4]) {
  bf16x8 a[4], b[4];
#pragma unroll
  for (int i = 0; i < 4; i++)
    a[i] = *reinterpret_cast<const bf16x8*>(&As[(wm + i * 16 + l16) * BK + quad * 8]);
#pragma unroll
  for (int j = 0; j < 4; j++)
    b[j] = *reinterpret_cast<const bf16x8*>(&Bs[(wn + j * 16 + l16) * BK + quad * 8]);
#pragma unroll
  for (int i = 0; i < 4; i++)
#pragma unroll
    for (int j = 0; j < 4; j++)
      acc[i][j] = __builtin_amdgcn_mfma_f32_16x16x32_bf16(a[i], b[j], acc[i][j], 0, 0, 0);
}

// ---------------- prep: fp32->bf16 convert (q,k,v) + weight transpose, one dispatch ----------------
// blocks [0,24576): convert; z = id>>13, chunk = id&8191, 2048 elems each.
// blocks [24576,27648): wt_transpose; z, 32x32 tile.
__global__ void prep(const float* __restrict__ q, const float* __restrict__ k,
                     const float* __restrict__ v, u16* __restrict__ Xall,
                     const float* __restrict__ Wq, const float* __restrict__ Wk,
                     const float* __restrict__ Wv, u16* __restrict__ Wall) {
  __shared__ u16 t[32][33];
  int id = blockIdx.x;
  if (id < 24576) {
    int z = id >> 13;
    int chunk = id & 8191;
    const float* x = (z == 0) ? q : (z == 1) ? k : v;
    u16* y = Xall + (size_t)z * (BB * SS * DD);
    size_t i = (size_t)chunk * 256 + threadIdx.x;
    const float4* s = (const float4*)x;
    float4 a = s[2 * i], b = s[2 * i + 1];
    uint4 p;
    p.x = (unsigned)f2bf(a.x) | ((unsigned)f2bf(a.y) << 16);
    p.y = (unsigned)f2bf(a.z) | ((unsigned)f2bf(a.w) << 16);
    p.z = (unsigned)f2bf(b.x) | ((unsigned)f2bf(b.y) << 16);
    p.w = (unsigned)f2bf(b.z) | ((unsigned)f2bf(b.w) << 16);
    ((uint4*)y)[i] = p;
  } else {
    int tt = id - 24576;
    int z = tt >> 10, t2 = tt & 1023;
    const float* W = (z == 0) ? Wq : (z == 1) ? Wk : Wv;
    u16* Wt = Wall + (size_t)z * (DD * DD);
    int n0 = (t2 & 31) * 32, k0 = (t2 >> 5) * 32;
    int tx = threadIdx.x & 31, ty = threadIdx.x >> 5;
#pragma unroll
    for (int i = 0; i < 32; i += 8)
      t[ty + i][tx] = f2bf(W[(size_t)(k0 + ty + i) * DD + n0 + tx]);
    __syncthreads();
#pragma unroll
    for (int i = 0; i < 32; i += 8)
      Wt[(size_t)(n0 + ty + i) * DD + k0 + tx] = t[tx][ty + i];
  }
}

// ---------------- fused projection GEMM, XCD-swizzled, BK=64 macro-iters ----------------
// z<2:  acc[m][n] = X@W,   writes Q/K  [b*S+s][d] bf16 (+bias[n])
// z==2: operands swapped -> acc[d][s] = (X@W)^T, writes Vt[b][d][s] bf16 (+bias[d])
__global__ void proj_gemm(const u16* __restrict__ Xall, const u16* __restrict__ Wall,
                          const float* __restrict__ bq, const float* __restrict__ bk,
                          const float* __restrict__ bv, u16* __restrict__ QK,
                          u16* __restrict__ Vt) {
  __shared__ __align__(16) u16 As[2 * TSZ];
  __shared__ __align__(16) u16 Bs[2 * TSZ];
  int id = blockIdx.x;
  int z = id >> 10, rem = id & 1023;
  int r = rem & 7, j = rem >> 3;
  int bn = j & 7, bm = ((j >> 3) << 3) | r;   // same-XCD blocks share X panel; W L2-hot
  const u16* Xb = Xall + (size_t)z * (BB * SS * DD);
  const u16* Wt = Wall + (size_t)z * (DD * DD);
  const float* bias = (z == 0) ? bq : (z == 1) ? bk : bv;
  int m0 = bm * 128, n0 = bn * 128;
  int tid = threadIdx.x;
  int lane = tid & 63, wave = tid >> 6;
  int wm = (wave >> 1) * 64, wn = (wave & 1) * 64;
  int quad = lane >> 4, l16 = lane & 15;

  // operand roles: As rows -> acc rows, Bs rows -> acc cols
  const u16* Abase = (z < 2) ? (Xb + (size_t)m0 * DD) : (Wt + (size_t)n0 * DD);
  const u16* Bbase = (z < 2) ? (Wt + (size_t)n0 * DD) : (Xb + (size_t)m0 * DD);

  f32x4 acc[4][4];
  f32x4 zz = {0.f, 0.f, 0.f, 0.f};
#pragma unroll
  for (int i = 0; i < 4; i++)
#pragma unroll
    for (int jj = 0; jj < 4; jj++) acc[i][jj] = zz;

  for (int k0 = 0; k0 < DD; k0 += 2 * BK) {
    __syncthreads();
    stage_tile(Abase + k0, DD, As, wave, lane);
    stage_tile(Abase + k0 + BK, DD, As + TSZ, wave, lane);
    stage_tile(Bbase + k0, DD, Bs, wave, lane);
    stage_tile(Bbase + k0 + BK, DD, Bs + TSZ, wave, lane);
    __syncthreads();
    mfma_tile(As, Bs, wm, wn, quad, l16, acc);
    mfma_tile(As + TSZ, Bs + TSZ, wm, wn, quad, l16, acc);
  }
  if (z < 2) {
    u16* Out = QK + (size_t)z * (BB * SS * DD);
#pragma unroll
    for (int i = 0; i < 4; i++) {
#pragma unroll
      for (int rr = 0; rr < 4; rr++) {
        int row = m0 + wm + i * 16 + quad * 4 + rr;
#pragma unroll
        for (int jj = 0; jj < 4; jj++) {
          int col = n0 + wn + jj * 16 + l16;
          Out[(size_t)row * DD + col] = f2bf(acc[i][jj][rr] + bias[col]);
        }
      }
    }
  } else {
    int b = m0 >> 11, s0 = m0 & 2047;
#pragma unroll
    for (int i = 0; i < 4; i++) {
#pragma unroll
      for (int rr = 0; rr < 4; rr++) {
        int d = n0 + wm + i * 16 + quad * 4 + rr;   // acc row = W col index
        float bd = bias[d];
#pragma unroll
        for (int jj = 0; jj < 4; jj++) {
          int s = s0 + wn + jj * 16 + l16;          // acc col = X row index
          Vt[((size_t)b * DD + d) * SS + s] = f2bf(acc[i][jj][rr] + bd);
        }
      }
    }
  }
}

// ---------------- causal scores GEMM, triangular-compacted, BK=64 macro ----------------
// id in [0,1088): b = id&7 (XCD residue = batch), t = id>>3 (triangular tile id).
__global__ void scores_gemm(const u16* __restrict__ Q, const u16* __restrict__ Kp,
                            u16* __restrict__ Sc) {
  __shared__ __align__(16) u16 As[2 * TSZ];
  __shared__ __align__(16) u16 Bs[2 * TSZ];
  int id = blockIdx.x;
  int b = id & 7, t = id >> 3;
  int bm = (int)((sqrtf(8.f * t + 1.f) - 1.f) * 0.5f);
  while ((bm + 1) * (bm + 2) / 2 <= t) bm++;
  while (bm * (bm + 1) / 2 > t) bm--;
  int bn = t - bm * (bm + 1) / 2;

  const u16* Qb = Q + (size_t)b * SS * DD;
  const u16* Kb = Kp + (size_t)b * SS * DD;
  u16* Sb = Sc + (size_t)b * SS * SS;
  int m0 = bm * 128, n0 = bn * 128;
  int tid = threadIdx.x;
  int lane = tid & 63, wave = tid >> 6;
  int wm = (wave >> 1) * 64, wn = (wave & 1) * 64;
  int quad = lane >> 4, l16 = lane & 15;

  f32x4 acc[4][4];
  f32x4 z = {0.f, 0.f, 0.f, 0.f};
#pragma unroll
  for (int i = 0; i < 4; i++)
#pragma unroll
    for (int jj = 0; jj < 4; jj++) acc[i][jj] = z;

  for (int k0 = 0; k0 < DD; k0 += 2 * BK) {
    __syncthreads();
    stage_tile(Qb + (size_t)m0 * DD + k0, DD, As, wave, lane);
    stage_tile(Qb + (size_t)m0 * DD + k0 + BK, DD, As + TSZ, wave, lane);
    stage_tile(Kb + (size_t)n0 * DD + k0, DD, Bs, wave, lane);
    stage_tile(Kb + (size_t)n0 * DD + k0 + BK, DD, Bs + TSZ, wave, lane);
    __syncthreads();
    mfma_tile(As, Bs, wm, wn, quad, l16, acc);
    mfma_tile(As + TSZ, Bs + TSZ, wm, wn, quad, l16, acc);
  }
#pragma unroll
  for (int i = 0; i < 4; i++) {
#pragma unroll
    for (int rr = 0; rr < 4; rr++) {
      int gi = m0 + wm + i * 16 + quad * 4 + rr;
#pragma unroll
      for (int jj = 0; jj < 4; jj++) {
        int gj = n0 + wn + jj * 16 + l16;
        if (gj <= gi) Sb[(size_t)gi * SS + gj] = f2bf(acc[i][jj][rr] * 0.03125f);
      }
    }
  }
}

// ---------------- row softmax, causal-truncated to roundup(i+1,128) ----------------
__global__ void softmax_causal(const u16* __restrict__ Sc, u16* __restrict__ P) {
  int i = blockIdx.x, b = blockIdx.y;
  const u16* srow = Sc + ((size_t)b * SS + i) * SS;
  u16* prow = P + ((size_t)b * SS + i) * SS;
  int n = i + 1;
  int nceil = ((i >> 7) + 1) << 7;  // pv reads only [0, roundup64(n)) ⊆ [0, nceil)
  int tid = threadIdx.x;
  int lane = tid & 63, wave = tid >> 6;
  __shared__ float sm[4];
  __shared__ float ssum[4];

  int j0 = tid * 8;
  bool act = j0 < nceil;
  float v[8];
  float mx = -3.0e38f;
  if (act) {
    uint4 raw = ((const uint4*)srow)[tid];
    unsigned w[4] = {raw.x, raw.y, raw.z, raw.w};
#pragma unroll
    for (int u = 0; u < 8; u++) {
      u16 h = (u16)((w[u >> 1] >> ((u & 1) * 16)) & 0xffffu);
      v[u] = (j0 + u < n) ? bf2f(h) : -3.0e38f;
      mx = fmaxf(mx, v[u]);
    }
  } else {
#pragma unroll
    for (int u = 0; u < 8; u++) v[u] = -3.0e38f;
  }
#pragma unroll
  for (int off = 32; off > 0; off >>= 1) mx = fmaxf(mx, __shfl_down(mx, off, 64));
  if (lane == 0) sm[wave] = mx;
  __syncthreads();
  mx = fmaxf(fmaxf(sm[0], sm[1]), fmaxf(sm[2], sm[3]));

  float e[8];
  float sum = 0.f;
#pragma unroll
  for (int u = 0; u < 8; u++) {
    e[u] = __expf(v[u] - mx);  // masked -> 0
    sum += e[u];
  }
#pragma unroll
  for (int off = 32; off > 0; off >>= 1) sum += __shfl_down(sum, off, 64);
  if (lane == 0) ssum[wave] = sum;
  __syncthreads();
  sum = ssum[0] + ssum[1] + ssum[2] + ssum[3];
  float inv = 1.0f / sum;
  if (act) {
    uint4 o;
    unsigned* ow = (unsigned*)&o;
#pragma unroll
    for (int u = 0; u < 4; u++) {
      u16 lo = f2bf(e[2 * u] * inv);
      u16 hi = f2bf(e[2 * u + 1] * inv);
      ow[u] = (unsigned)lo | ((unsigned)hi << 16);
    }
    ((uint4*)prow)[tid] = o;
  }
}

// ---------------- PV GEMM, 64x128 tiles, paired m-tiles, BK=64 macro ----------------
// id in [0,1024): bn = id&7 (XCD residue -> Vt slice L2-hot), q = (id>>3)&15, b = id>>7.
// Phases bm = q and 31-q: macro K-iters (q+1)+(32-q) = 33, uniform.
__global__ void pv_gemm(const u16* __restrict__ P, const u16* __restrict__ Vt,
                        float* __restrict__ O) {
  __shared__ __align__(16) u16 As[2 * 64 * BK];
  __shared__ __align__(16) u16 Bs[2 * TSZ];
  int id = blockIdx.x;
  int bn = id & 7, q = (id >> 3) & 15, b = id >> 7;
  const u16* Pb = P + (size_t)b * SS * SS;
  const u16* Vb = Vt + (size_t)b * SS * DD;  // [d][s]
  float* Ob = O + (size_t)b * SS * DD;
  int n0 = bn * 128;
  int tid = threadIdx.x;
  int lane = tid & 63, wave = tid >> 6;
  int wn = wave * 32;
  int quad = lane >> 4, l16 = lane & 15;

#pragma unroll
  for (int phase = 0; phase < 2; phase++) {
    int bm = phase ? (31 - q) : q;
    int m0 = bm * 64;
    f32x4 acc[4][2];
    f32x4 z = {0.f, 0.f, 0.f, 0.f};
#pragma unroll
    for (int i = 0; i < 4; i++)
#pragma unroll
      for (int jj = 0; jj < 2; jj++) acc[i][jj] = z;

    int kmax = (bm + 1) * 64;  // P[m][k]==0 for k>m; multiple of 64
    for (int k0 = 0; k0 < kmax; k0 += 2 * BK) {
      __syncthreads();
#pragma unroll
      for (int sub = 0; sub < 2; sub++) {  // A: 64 rows x 32, one issue per wave each
        int row = wave * 16 + (lane >> 2);
        int col = (lane & 3) * 8;
        gl2lds16(Pb + (size_t)(m0 + row) * SS + k0 + sub * BK + col,
                 As + sub * 64 * BK + wave * 16 * BK);
      }
      stage_tile(Vb + (size_t)n0 * SS + k0, SS, Bs, wave, lane);
      stage_tile(Vb + (size_t)n0 * SS + k0 + BK, SS, Bs + TSZ, wave, lane);
      __syncthreads();
#pragma unroll
      for (int sub = 0; sub < 2; sub++) {
        const u16* Asub = As + sub * 64 * BK;
        const u16* Bsub = Bs + sub * TSZ;
        bf16x8 a[4], bb[2];
#pragma unroll
        for (int i = 0; i < 4; i++)
          a[i] = *reinterpret_cast<const bf16x8*>(&Asub[(i * 16 + l16) * BK + quad * 8]);
#pragma unroll
        for (int jj = 0; jj < 2; jj++)
          bb[jj] = *reinterpret_cast<const bf16x8*>(&Bsub[(wn + jj * 16 + l16) * BK + quad * 8]);
#pragma unroll
        for (int i = 0; i < 4; i++)
#pragma unroll
          for (int jj = 0; jj < 2; jj++)
            acc[i][jj] = __builtin_amdgcn_mfma_f32_16x16x32_bf16(a[i], bb[jj], acc[i][jj], 0, 0, 0);
      }
    }
#pragma unroll
    for (int i = 0; i < 4; i++) {
#pragma unroll
      for (int rr = 0; rr < 4; rr++) {
        int row = m0 + i * 16 + quad * 4 + rr;
#pragma unroll
        for (int jj = 0; jj < 2; jj++) {
          int col = n0 + wn + jj * 16 + l16;
          Ob[(size_t)row * DD + col] = acc[i][jj][rr];
        }
      }
    }
  }
}

extern "C" void kernel_launch(void* const* d_in, const int* in_sizes, int n_in,
                              void* d_out, int out_size, void* d_ws, size_t ws_size,
                              hipStream_t stream) {
  const float* query = (const float*)d_in[0];
  const float* key_ = (const float*)d_in[1];
  const float* value = (const float*)d_in[2];
  // d_in[3] = causal mask -- implemented structurally
  const float* Wq = (const float*)d_in[4];
  const float* bq = (const float*)d_in[5];
  const float* Wk = (const float*)d_in[6];
  const float* bk = (const float*)d_in[7];
  const float* Wv = (const float*)d_in[8];
  const float* bv = (const float*)d_in[9];
  float* out = (float*)d_out;
  char* ws = (char*)d_ws;

  const size_t MB = 1048576ull;
  // Workspace (peak 198 MB), stream-ordered lifetime aliasing:
  //  Xall [0,96)    3x bf16 activations (read by proj; dead after)
  //  QK   [96,160)  Qb/Kb bf16
  //  Vt   [160,192) bf16 [b][d][s], written by proj z==2
  //  Wall [192,198) 3x Wt bf16
  //  Sc   [32,96)   bf16 64 MB, over dead Xall (after proj)
  //  P    [96,160)  bf16 64 MB, over dead Qb/Kb (after scores)
  u16* Xall = (u16*)(ws + 0);
  u16* QK   = (u16*)(ws + 96 * MB);
  u16* Qb   = (u16*)(ws + 96 * MB);
  u16* Kb   = (u16*)(ws + 128 * MB);
  u16* Vt   = (u16*)(ws + 160 * MB);
  u16* Wall = (u16*)(ws + 192 * MB);
  u16* Sc   = (u16*)(ws + 32 * MB);
  u16* P    = (u16*)(ws + 96 * MB);

  dim3 blk(256, 1, 1);
  prep<<<dim3(27648, 1, 1), blk, 0, stream>>>(query, key_, value, Xall, Wq, Wk, Wv, Wall);
  proj_gemm<<<dim3(3072, 1, 1), blk, 0, stream>>>(Xall, Wall, bq, bk, bv, QK, Vt);
  scores_gemm<<<dim3(1088, 1, 1), blk, 0, stream>>>(Qb, Kb, Sc);
  softmax_causal<<<dim3(2048, 8, 1), blk, 0, stream>>>(Sc, P);
  pv_gemm<<<dim3(1024, 1, 1), blk, 0, stream>>>(P, Vt, out);
}